// Round 2
// baseline (812.440 us; speedup 1.0000x reference)
//
#include <hip/hip_runtime.h>
#include <hip/hip_bf16.h>
#include <stdint.h>

// TrajectoryDecoder: B=65536 fused LSTM rollout, H=64, T=64.
// Round 2: near-fp32 precision via split-bf16 (hi+lo) MFMA.
//  - prev/pred folded: W_eff = W_hh + W_prev@W_out, wpb = W_prev@b_out.
//  - gates = W_hi*h_hi + W_hi*h_lo + W_lo*h_hi (3-term, ~fp32), gs kept fp32
//    in regs, c-state fp32 in regs. Init GEMMs (h0/c0/gs) also 3-term.
//  - One wave = 16 batch rows; W_eff hi+lo resident in 256 VGPRs ->
//    __launch_bounds__(64,1). h round-trips via 4KB XOR-swizzled LDS as
//    hi+lo pairs. Preds buffered in LDS, flushed coalesced.

typedef unsigned short u16;
typedef unsigned int u32;
typedef __bf16 bf16x8 __attribute__((ext_vector_type(8)));
typedef u16 u16x8 __attribute__((ext_vector_type(8)));
typedef float f32x4 __attribute__((ext_vector_type(4)));
typedef float f32x2 __attribute__((ext_vector_type(2)));

#define MFMA16(a, b, c) __builtin_amdgcn_mfma_f32_16x16x32_bf16((a), (b), (c), 0, 0, 0)

__device__ __forceinline__ u16 f2bf(float f) {
  __bf16 h = (__bf16)f;
  return __builtin_bit_cast(u16, h);
}
__device__ __forceinline__ float bf2f(u16 u) {
  return __builtin_bit_cast(float, ((u32)u) << 16);
}
__device__ __forceinline__ u32 pkbf(float lo, float hi) {
  union { __bf16 b[2]; u32 u; } p;
  p.b[0] = (__bf16)lo;
  p.b[1] = (__bf16)hi;
  return p.u;
}
__device__ __forceinline__ bf16x8 ldfrag_g(const u16* p) {
  u16x8 v = *(const u16x8*)p;
  return __builtin_bit_cast(bf16x8, v);
}
// split fp32[8] -> bf16 hi + bf16 lo fragments
__device__ __forceinline__ void split8(const float* v, bf16x8& hi, bf16x8& lo) {
  union { u16 s[8]; bf16x8 b; } H, L;
#pragma unroll
  for (int i = 0; i < 8; i++) {
    u16 h = f2bf(v[i]);
    H.s[i] = h;
    L.s[i] = f2bf(v[i] - bf2f(h));
  }
  hi = H.b;
  lo = L.b;
}
__device__ __forceinline__ float sigm(float x) {
  float e = __builtin_amdgcn_exp2f(-1.442695040888963f * x);
  return __builtin_amdgcn_rcpf(1.f + e);
}
__device__ __forceinline__ float tanh_(float x) {
  float e = __builtin_amdgcn_exp2f(2.885390081777927f * x);
  return 1.f - 2.f * __builtin_amdgcn_rcpf(1.f + e);
}
__device__ __forceinline__ void nonlin4(const f32x4 ai, const f32x4 af, const f32x4 ag,
                                        const f32x4 ao, f32x4& crow, u32& w0h, u32& w1h,
                                        u32& w0l, u32& w1l) {
  float hi[4], lo[4];
#pragma unroll
  for (int q = 0; q < 4; q++) {
    float iv = sigm(ai[q]);
    float fv = sigm(af[q]);
    float gv = tanh_(ag[q]);
    float ov = sigm(ao[q]);
    float cc = fv * crow[q] + iv * gv;
    crow[q] = cc;
    float hh = ov * tanh_(cc);
    u16 h16 = f2bf(hh);
    hi[q] = bf2f(h16);
    lo[q] = hh - hi[q];
  }
  w0h = pkbf(hi[0], hi[1]);
  w1h = pkbf(hi[2], hi[3]);
  w0l = pkbf(lo[0], lo[1]);
  w1l = pkbf(lo[2], lo[3]);
}

// ---------------- setup kernel: hi/lo bf16 weights + folded matrices ----------------
__global__ void setup_k(const float* __restrict__ Wh_ctx, const float* __restrict__ Wc_ctx,
                        const float* __restrict__ W_ih, const float* __restrict__ W_hh,
                        const float* __restrict__ b_ih, const float* __restrict__ b_hh,
                        const float* __restrict__ W_out, const float* __restrict__ b_out,
                        u16* __restrict__ weffH, u16* __restrict__ weffL,
                        u16* __restrict__ whhH, u16* __restrict__ whhL,
                        u16* __restrict__ wstatH, u16* __restrict__ wstatL,
                        u16* __restrict__ whcH, u16* __restrict__ whcL,
                        u16* __restrict__ wccH, u16* __restrict__ wccL,
                        float* __restrict__ bsum, float* __restrict__ wpbv) {
  int gr = (int)threadIdx.x;  // 0..255
  float wp0 = W_ih[gr * 68 + 0];
  float wp1 = W_ih[gr * 68 + 1];
  for (int k = 0; k < 64; k++) {
    float whh = W_hh[gr * 64 + k];
    u16 h = f2bf(whh);
    whhH[gr * 64 + k] = h;
    whhL[gr * 64 + k] = f2bf(whh - bf2f(h));
    float we = whh + wp0 * W_out[k] + wp1 * W_out[64 + k];
    u16 eh = f2bf(we);
    weffH[gr * 64 + k] = eh;
    weffL[gr * 64 + k] = f2bf(we - bf2f(eh));
  }
  for (int k = 0; k < 96; k++) {
    float v = (k < 66) ? W_ih[gr * 68 + 2 + k] : 0.f;
    u16 h = f2bf(v);
    wstatH[gr * 96 + k] = h;
    wstatL[gr * 96 + k] = f2bf(v - bf2f(h));
  }
  float wpb_ = wp0 * b_out[0] + wp1 * b_out[1];
  wpbv[gr] = wpb_;
  bsum[gr] = b_ih[gr] + b_hh[gr] + wpb_;
  if (gr < 64) {
    for (int k = 0; k < 128; k++) {
      float a = Wh_ctx[gr * 128 + k];
      u16 ah = f2bf(a);
      whcH[gr * 128 + k] = ah;
      whcL[gr * 128 + k] = f2bf(a - bf2f(ah));
      float b = Wc_ctx[gr * 128 + k];
      u16 bh_ = f2bf(b);
      wccH[gr * 128 + k] = bh_;
      wccL[gr * 128 + k] = f2bf(b - bf2f(bh_));
    }
  }
}

// LDS h buffers: [region][row c][64 bf16], XOR-swizzled within 128B rows.
#define HFRAG(base, f) \
  ldfrag_g((const u16*)((const char*)(base) + c * 128 + (((16 * g) + 64 * (f)) ^ sw4)))

#define HWRITE(base, grp, w0, w1)                                \
  do {                                                           \
    char* bp_ = (char*)(base) + c * 128;                         \
    *(u32*)(bp_ + ((32 * (grp) + 8 * g) ^ sw4)) = (w0);          \
    *(u32*)(bp_ + ((32 * (grp) + 8 * g + 4) ^ sw4)) = (w1);      \
  } while (0)

// ---------------- main fused kernel ----------------
__global__ __launch_bounds__(64, 1) void traj_main(
    const float* __restrict__ ctx, const float* __restrict__ enc,
    const float* __restrict__ ball, const float* __restrict__ bh,
    const float* __restrict__ bc, const float* __restrict__ bout,
    const float* __restrict__ woutf, const u16* __restrict__ weffH,
    const u16* __restrict__ weffL, const u16* __restrict__ whhH,
    const u16* __restrict__ whhL, const u16* __restrict__ wstatH,
    const u16* __restrict__ wstatL, const u16* __restrict__ whcH,
    const u16* __restrict__ whcL, const u16* __restrict__ wccH,
    const u16* __restrict__ wccL, const float* __restrict__ bsum,
    const float* __restrict__ wpbv, float* __restrict__ out) {
  __shared__ __align__(16) u16 hH_sh[16 * 64];       // h hi
  __shared__ __align__(16) u16 hL_sh[16 * 64];       // h lo
  __shared__ __align__(16) float p_sh[16 * 64 * 2];  // preds

  const int lane = (int)(threadIdx.x & 63u);
  const int c = lane & 15;   // batch row within tile (MFMA col)
  const int g = lane >> 4;   // lane group
  const int sw4 = (c & 7) << 4;
  const int b0 = (int)blockIdx.x * 16;
  const size_t row = (size_t)(b0 + c);

  // ---- context B-frags hi/lo (K=128 -> 4 frags each) ----
  bf16x8 xcH[4], xcL[4];
#pragma unroll
  for (int kk = 0; kk < 4; kk++) {
    const float* p = ctx + row * 128 + 32 * kk + 8 * g;
    f32x4 a = *(const f32x4*)p;
    f32x4 b = *(const f32x4*)(p + 4);
    float v[8] = {a[0], a[1], a[2], a[3], b[0], b[1], b[2], b[3]};
    split8(v, xcH[kk], xcL[kk]);
  }

  // ---- h0 = ctx @ Wh^T + bh (3-term), straight into swizzled LDS hi/lo ----
#pragma unroll
  for (int tn = 0; tn < 4; tn++) {
    f32x4 acc = *(const f32x4*)(bh + 16 * tn + 4 * g);
#pragma unroll
    for (int kk = 0; kk < 4; kk++) {
      bf16x8 aH = ldfrag_g(whcH + (16 * tn + c) * 128 + 32 * kk + 8 * g);
      bf16x8 aL = ldfrag_g(whcL + (16 * tn + c) * 128 + 32 * kk + 8 * g);
      acc = MFMA16(aH, xcH[kk], acc);
      acc = MFMA16(aH, xcL[kk], acc);
      acc = MFMA16(aL, xcH[kk], acc);
    }
    float hi_[4], lo_[4];
#pragma unroll
    for (int q = 0; q < 4; q++) {
      u16 h16 = f2bf(acc[q]);
      hi_[q] = bf2f(h16);
      lo_[q] = acc[q] - hi_[q];
    }
    HWRITE(hH_sh, tn, pkbf(hi_[0], hi_[1]), pkbf(hi_[2], hi_[3]));
    HWRITE(hL_sh, tn, pkbf(lo_[0], lo_[1]), pkbf(lo_[2], lo_[3]));
  }

  // ---- c0 = ctx @ Wc^T + bc (3-term), fp32 resident ----
  f32x4 cst[4];
#pragma unroll
  for (int tn = 0; tn < 4; tn++) {
    f32x4 acc = *(const f32x4*)(bc + 16 * tn + 4 * g);
#pragma unroll
    for (int kk = 0; kk < 4; kk++) {
      bf16x8 aH = ldfrag_g(wccH + (16 * tn + c) * 128 + 32 * kk + 8 * g);
      bf16x8 aL = ldfrag_g(wccL + (16 * tn + c) * 128 + 32 * kk + 8 * g);
      acc = MFMA16(aH, xcH[kk], acc);
      acc = MFMA16(aH, xcL[kk], acc);
      acc = MFMA16(aL, xcH[kk], acc);
    }
    cst[tn] = acc;
  }

  // ---- static input frags hi/lo: [ball(2), enc(64), 0-pad] K=96 ----
  bf16x8 xsH[3], xsL[3];
#pragma unroll
  for (int kk = 0; kk < 3; kk++) {
    float v[8];
#pragma unroll
    for (int j = 0; j < 8; j++) {
      int k = 32 * kk + 8 * g + j;
      float val = 0.f;
      if (k < 2) val = ball[row * 2 + k];
      else if (k < 66) val = enc[row * 64 + (k - 2)];
      v[j] = val;
    }
    split8(v, xsH[kk], xsL[kk]);
  }

  // ---- gates_static (incl. b_ih+b_hh+wpb), fp32 resident (3-term) ----
  f32x4 gsf[16];
#pragma unroll
  for (int tl = 0; tl < 16; tl++) {
    f32x4 acc = *(const f32x4*)(bsum + 16 * tl + 4 * g);
#pragma unroll
    for (int kk = 0; kk < 3; kk++) {
      bf16x8 aH = ldfrag_g(wstatH + (16 * tl + c) * 96 + 32 * kk + 8 * g);
      bf16x8 aL = ldfrag_g(wstatL + (16 * tl + c) * 96 + 32 * kk + 8 * g);
      acc = MFMA16(aH, xsH[kk], acc);
      acc = MFMA16(aH, xsL[kk], acc);
      acc = MFMA16(aL, xsH[kk], acc);
    }
    gsf[tl] = acc;
  }

  // ---- W_out as zero-padded 16x64 A-tile (rows 0,1) for pred MFMA ----
  bf16x8 wof[2];
#pragma unroll
  for (int f = 0; f < 2; f++) {
    float v[8];
#pragma unroll
    for (int j = 0; j < 8; j++) {
      int k = 32 * f + 8 * g + j;
      v[j] = (c < 2) ? woutf[c * 64 + k] : 0.f;
    }
    bf16x8 dummy;
    split8(v, wof[f], dummy);
  }
  const float bo0 = bout[0], bo1 = bout[1];

  // ---- step 0 (peeled): W_hh (hi/lo streamed from global), gs - wpb ----
  {
    bf16x8 hh0 = HFRAG(hH_sh, 0), hh1 = HFRAG(hH_sh, 1);
    bf16x8 hl0 = HFRAG(hL_sh, 0), hl1 = HFRAG(hL_sh, 1);
#pragma unroll
    for (int grp = 0; grp < 4; grp++) {
      f32x4 av[4];
#pragma unroll
      for (int t = 0; t < 4; t++) {
        int tl = grp + 4 * t;
        f32x4 acc = gsf[tl] - *(const f32x4*)(wpbv + 16 * tl + 4 * g);
        bf16x8 aH0 = ldfrag_g(whhH + (16 * tl + c) * 64 + 8 * g);
        bf16x8 aH1 = ldfrag_g(whhH + (16 * tl + c) * 64 + 32 + 8 * g);
        bf16x8 aL0 = ldfrag_g(whhL + (16 * tl + c) * 64 + 8 * g);
        bf16x8 aL1 = ldfrag_g(whhL + (16 * tl + c) * 64 + 32 + 8 * g);
        acc = MFMA16(aH0, hh0, acc);
        acc = MFMA16(aH1, hh1, acc);
        acc = MFMA16(aH0, hl0, acc);
        acc = MFMA16(aH1, hl1, acc);
        acc = MFMA16(aL0, hh0, acc);
        acc = MFMA16(aL1, hh1, acc);
        av[t] = acc;
      }
      u32 w0h, w1h, w0l, w1l;
      nonlin4(av[0], av[1], av[2], av[3], cst[grp], w0h, w1h, w0l, w1l);
      HWRITE(hH_sh, grp, w0h, w1h);
      HWRITE(hL_sh, grp, w0l, w1l);
    }
  }

  // ---- W_eff hi/lo frags resident (256 VGPRs) ----
  bf16x8 wfH[16][2], wfL[16][2];
#pragma unroll
  for (int tl = 0; tl < 16; tl++) {
#pragma unroll
    for (int f = 0; f < 2; f++) {
      wfH[tl][f] = ldfrag_g(weffH + (16 * tl + c) * 64 + 32 * f + 8 * g);
      wfL[tl][f] = ldfrag_g(weffL + (16 * tl + c) * 64 + 32 * f + 8 * g);
    }
  }

  // ---- steps 1..63 ----
#pragma unroll 1
  for (int k = 1; k < 64; k++) {
    bf16x8 hh0 = HFRAG(hH_sh, 0), hh1 = HFRAG(hH_sh, 1);
    bf16x8 hl0 = HFRAG(hL_sh, 0), hl1 = HFRAG(hL_sh, 1);
    f32x4 pacc = {bo0, bo1, 0.f, 0.f};
    pacc = MFMA16(wof[0], hh0, pacc);
    pacc = MFMA16(wof[1], hh1, pacc);
    if (g == 0) {
      f32x2 pr = {pacc[0], pacc[1]};
      *(f32x2*)((char*)p_sh + c * 512 + (((k - 1) * 8) ^ ((c & 7) << 3))) = pr;
    }
#pragma unroll
    for (int grp = 0; grp < 4; grp++) {
      f32x4 av[4];
#pragma unroll
      for (int t = 0; t < 4; t++) {
        int tl = grp + 4 * t;
        f32x4 acc = gsf[tl];
        acc = MFMA16(wfH[tl][0], hh0, acc);
        acc = MFMA16(wfH[tl][1], hh1, acc);
        acc = MFMA16(wfH[tl][0], hl0, acc);
        acc = MFMA16(wfH[tl][1], hl1, acc);
        acc = MFMA16(wfL[tl][0], hh0, acc);
        acc = MFMA16(wfL[tl][1], hh1, acc);
        av[t] = acc;
      }
      u32 w0h, w1h, w0l, w1l;
      nonlin4(av[0], av[1], av[2], av[3], cst[grp], w0h, w1h, w0l, w1l);
      HWRITE(hH_sh, grp, w0h, w1h);
      HWRITE(hL_sh, grp, w0l, w1l);
    }
  }

  // ---- final pred_63 ----
  {
    bf16x8 hh0 = HFRAG(hH_sh, 0), hh1 = HFRAG(hH_sh, 1);
    f32x4 pacc = {bo0, bo1, 0.f, 0.f};
    pacc = MFMA16(wof[0], hh0, pacc);
    pacc = MFMA16(wof[1], hh1, pacc);
    if (g == 0) {
      f32x2 pr = {pacc[0], pacc[1]};
      *(f32x2*)((char*)p_sh + c * 512 + ((63 * 8) ^ ((c & 7) << 3))) = pr;
    }
  }

  // ---- coalesced flush: out[b][t][2] ----
#pragma unroll
  for (int r = 0; r < 16; r++) {
    f32x2 v = *(const f32x2*)((const char*)p_sh + r * 512 + ((lane * 8) ^ ((r & 7) << 3)));
    *(f32x2*)(out + (size_t)(b0 + r) * 128 + lane * 2) = v;
  }
}

extern "C" void kernel_launch(void* const* d_in, const int* in_sizes, int n_in,
                              void* d_out, int out_size, void* d_ws, size_t ws_size,
                              hipStream_t stream) {
  const float* ctx = (const float*)d_in[0];
  const float* enc = (const float*)d_in[1];
  const float* ball = (const float*)d_in[2];
  const float* Wh = (const float*)d_in[3];
  const float* bh = (const float*)d_in[4];
  const float* Wc = (const float*)d_in[5];
  const float* bc = (const float*)d_in[6];
  const float* Wih = (const float*)d_in[7];
  const float* Whh = (const float*)d_in[8];
  const float* bih = (const float*)d_in[9];
  const float* bhh = (const float*)d_in[10];
  const float* Wout = (const float*)d_in[11];
  const float* bout = (const float*)d_in[12];
  float* out = (float*)d_out;

  char* ws = (char*)d_ws;
  u16* weffH = (u16*)(ws + 0);        // 256*64*2 = 32768
  u16* weffL = (u16*)(ws + 32768);    // 32768
  u16* whhH = (u16*)(ws + 65536);     // 32768
  u16* whhL = (u16*)(ws + 98304);     // 32768
  u16* wstatH = (u16*)(ws + 131072);  // 256*96*2 = 49152
  u16* wstatL = (u16*)(ws + 180224);  // 49152
  u16* whcH = (u16*)(ws + 229376);    // 64*128*2 = 16384
  u16* whcL = (u16*)(ws + 245760);    // 16384
  u16* wccH = (u16*)(ws + 262144);    // 16384
  u16* wccL = (u16*)(ws + 278528);    // 16384
  float* bsum = (float*)(ws + 294912);
  float* wpbv = (float*)(ws + 295936);

  const int B = in_sizes[0] / 128;

  setup_k<<<1, 256, 0, stream>>>(Wh, Wc, Wih, Whh, bih, bhh, Wout, bout, weffH, weffL,
                                 whhH, whhL, wstatH, wstatL, whcH, whcL, wccH, wccL,
                                 bsum, wpbv);
  traj_main<<<B / 16, 64, 0, stream>>>(ctx, enc, ball, bh, bc, bout, Wout, weffH, weffL,
                                       whhH, whhL, wstatH, wstatL, whcH, whcL, wccH,
                                       wccL, bsum, wpbv, out);
}

// Round 3
// 654.374 us; speedup vs baseline: 1.2416x; 1.2416x over previous
//
#include <hip/hip_runtime.h>
#include <hip/hip_bf16.h>
#include <stdint.h>

// TrajectoryDecoder: B=65536 fused LSTM rollout, H=64, T=64.
// Round 3: occupancy fix. 4-wave blocks, h-dimension split across waves.
//  - Wave w owns h-units [16w,16w+16) for all 4 gates (tiles tl=4j+w).
//    Per-wave weights: 64 VGPR (was 256) -> target 3 waves/SIMD.
//  - h (hi+lo bf16) exchanged via double-buffered XOR-swizzled LDS,
//    one __syncthreads() per step.
//  - Precision scheme unchanged from round 2 (3-term split-bf16, fp32 gs/c).

typedef unsigned short u16;
typedef unsigned int u32;
typedef __bf16 bf16x8 __attribute__((ext_vector_type(8)));
typedef u16 u16x8 __attribute__((ext_vector_type(8)));
typedef float f32x4 __attribute__((ext_vector_type(4)));
typedef float f32x2 __attribute__((ext_vector_type(2)));

#define MFMA16(a, b, c) __builtin_amdgcn_mfma_f32_16x16x32_bf16((a), (b), (c), 0, 0, 0)

__device__ __forceinline__ u16 f2bf(float f) {
  __bf16 h = (__bf16)f;
  return __builtin_bit_cast(u16, h);
}
__device__ __forceinline__ float bf2f(u16 u) {
  return __builtin_bit_cast(float, ((u32)u) << 16);
}
__device__ __forceinline__ u32 pkbf(float lo, float hi) {
  union { __bf16 b[2]; u32 u; } p;
  p.b[0] = (__bf16)lo;
  p.b[1] = (__bf16)hi;
  return p.u;
}
__device__ __forceinline__ bf16x8 ldfrag_g(const u16* p) {
  u16x8 v = *(const u16x8*)p;
  return __builtin_bit_cast(bf16x8, v);
}
__device__ __forceinline__ void split8(const float* v, bf16x8& hi, bf16x8& lo) {
  union { u16 s[8]; bf16x8 b; } H, L;
#pragma unroll
  for (int i = 0; i < 8; i++) {
    u16 h = f2bf(v[i]);
    H.s[i] = h;
    L.s[i] = f2bf(v[i] - bf2f(h));
  }
  hi = H.b;
  lo = L.b;
}
__device__ __forceinline__ float sigm(float x) {
  float e = __builtin_amdgcn_exp2f(-1.442695040888963f * x);
  return __builtin_amdgcn_rcpf(1.f + e);
}
__device__ __forceinline__ float tanh_(float x) {
  float e = __builtin_amdgcn_exp2f(2.885390081777927f * x);
  return 1.f - 2.f * __builtin_amdgcn_rcpf(1.f + e);
}
__device__ __forceinline__ void nonlin4(const f32x4 ai, const f32x4 af, const f32x4 ag,
                                        const f32x4 ao, f32x4& crow, u32& w0h, u32& w1h,
                                        u32& w0l, u32& w1l) {
  float hi[4], lo[4];
#pragma unroll
  for (int q = 0; q < 4; q++) {
    float iv = sigm(ai[q]);
    float fv = sigm(af[q]);
    float gv = tanh_(ag[q]);
    float ov = sigm(ao[q]);
    float cc = fv * crow[q] + iv * gv;
    crow[q] = cc;
    float hh = ov * tanh_(cc);
    u16 h16 = f2bf(hh);
    hi[q] = bf2f(h16);
    lo[q] = hh - hi[q];
  }
  w0h = pkbf(hi[0], hi[1]);
  w1h = pkbf(hi[2], hi[3]);
  w0l = pkbf(lo[0], lo[1]);
  w1l = pkbf(lo[2], lo[3]);
}

// ---------------- setup kernel: hi/lo bf16 weights + folded matrices ----------------
__global__ void setup_k(const float* __restrict__ Wh_ctx, const float* __restrict__ Wc_ctx,
                        const float* __restrict__ W_ih, const float* __restrict__ W_hh,
                        const float* __restrict__ b_ih, const float* __restrict__ b_hh,
                        const float* __restrict__ W_out, const float* __restrict__ b_out,
                        u16* __restrict__ weffH, u16* __restrict__ weffL,
                        u16* __restrict__ whhH, u16* __restrict__ whhL,
                        u16* __restrict__ wstatH, u16* __restrict__ wstatL,
                        u16* __restrict__ whcH, u16* __restrict__ whcL,
                        u16* __restrict__ wccH, u16* __restrict__ wccL,
                        float* __restrict__ bsum, float* __restrict__ wpbv) {
  int gr = (int)threadIdx.x;  // 0..255
  float wp0 = W_ih[gr * 68 + 0];
  float wp1 = W_ih[gr * 68 + 1];
  for (int k = 0; k < 64; k++) {
    float whh = W_hh[gr * 64 + k];
    u16 h = f2bf(whh);
    whhH[gr * 64 + k] = h;
    whhL[gr * 64 + k] = f2bf(whh - bf2f(h));
    float we = whh + wp0 * W_out[k] + wp1 * W_out[64 + k];
    u16 eh = f2bf(we);
    weffH[gr * 64 + k] = eh;
    weffL[gr * 64 + k] = f2bf(we - bf2f(eh));
  }
  for (int k = 0; k < 96; k++) {
    float v = (k < 66) ? W_ih[gr * 68 + 2 + k] : 0.f;
    u16 h = f2bf(v);
    wstatH[gr * 96 + k] = h;
    wstatL[gr * 96 + k] = f2bf(v - bf2f(h));
  }
  float wpb_ = wp0 * b_out[0] + wp1 * b_out[1];
  wpbv[gr] = wpb_;
  bsum[gr] = b_ih[gr] + b_hh[gr] + wpb_;
  if (gr < 64) {
    for (int k = 0; k < 128; k++) {
      float a = Wh_ctx[gr * 128 + k];
      u16 ah = f2bf(a);
      whcH[gr * 128 + k] = ah;
      whcL[gr * 128 + k] = f2bf(a - bf2f(ah));
      float b = Wc_ctx[gr * 128 + k];
      u16 bh_ = f2bf(b);
      wccH[gr * 128 + k] = bh_;
      wccL[gr * 128 + k] = f2bf(b - bf2f(bh_));
    }
  }
}

// LDS h buffers: [row c][64 bf16] = 128B rows, XOR-swizzled 16B slots.
#define HFRAG(base, f) \
  ldfrag_g((const u16*)((const char*)(base) + c * 128 + (((16 * g) + 64 * (f)) ^ sw4)))

#define HWRITE(base, grp, w0, w1)                                \
  do {                                                           \
    char* bp_ = (char*)(base) + c * 128;                         \
    *(u32*)(bp_ + ((32 * (grp) + 8 * g) ^ sw4)) = (w0);          \
    *(u32*)(bp_ + ((32 * (grp) + 8 * g + 4) ^ sw4)) = (w1);      \
  } while (0)

// ---------------- main fused kernel: 4 waves/block, h-split ----------------
__global__ __launch_bounds__(256, 3) void traj_main(
    const float* __restrict__ ctx, const float* __restrict__ enc,
    const float* __restrict__ ball, const float* __restrict__ bh,
    const float* __restrict__ bc, const float* __restrict__ bout,
    const float* __restrict__ woutf, const u16* __restrict__ weffH,
    const u16* __restrict__ weffL, const u16* __restrict__ whhH,
    const u16* __restrict__ whhL, const u16* __restrict__ wstatH,
    const u16* __restrict__ wstatL, const u16* __restrict__ whcH,
    const u16* __restrict__ whcL, const u16* __restrict__ wccH,
    const u16* __restrict__ wccL, const float* __restrict__ bsum,
    const float* __restrict__ wpbv, float* __restrict__ out) {
  __shared__ __align__(16) u16 hH_sh[2][16 * 64];    // h hi, double-buffered (2KB ea)
  __shared__ __align__(16) u16 hL_sh[2][16 * 64];    // h lo
  __shared__ __align__(16) float p_sh[16 * 64 * 2];  // preds (8KB)

  const int tid = (int)threadIdx.x;
  const int lane = tid & 63;
  const int w = tid >> 6;    // wave id 0..3: owns h-units [16w,16w+16)
  const int c = lane & 15;   // batch row within tile (MFMA col)
  const int g = lane >> 4;   // lane group
  const int sw4 = (c & 7) << 4;
  const int b0 = (int)blockIdx.x * 16;
  const size_t row = (size_t)(b0 + c);

  // ---- context B-frags hi/lo (K=128 -> 4 frags each) ----
  bf16x8 xcH[4], xcL[4];
#pragma unroll
  for (int kk = 0; kk < 4; kk++) {
    const float* p = ctx + row * 128 + 32 * kk + 8 * g;
    f32x4 a = *(const f32x4*)p;
    f32x4 b = *(const f32x4*)(p + 4);
    float v[8] = {a[0], a[1], a[2], a[3], b[0], b[1], b[2], b[3]};
    split8(v, xcH[kk], xcL[kk]);
  }

  // ---- h0 tile w: ctx @ Wh^T + bh (3-term) -> LDS buf0 ----
  {
    f32x4 acc = *(const f32x4*)(bh + 16 * w + 4 * g);
#pragma unroll
    for (int kk = 0; kk < 4; kk++) {
      bf16x8 aH = ldfrag_g(whcH + (16 * w + c) * 128 + 32 * kk + 8 * g);
      bf16x8 aL = ldfrag_g(whcL + (16 * w + c) * 128 + 32 * kk + 8 * g);
      acc = MFMA16(aH, xcH[kk], acc);
      acc = MFMA16(aH, xcL[kk], acc);
      acc = MFMA16(aL, xcH[kk], acc);
    }
    float hi_[4], lo_[4];
#pragma unroll
    for (int q = 0; q < 4; q++) {
      u16 h16 = f2bf(acc[q]);
      hi_[q] = bf2f(h16);
      lo_[q] = acc[q] - hi_[q];
    }
    HWRITE(hH_sh[0], w, pkbf(hi_[0], hi_[1]), pkbf(hi_[2], hi_[3]));
    HWRITE(hL_sh[0], w, pkbf(lo_[0], lo_[1]), pkbf(lo_[2], lo_[3]));
  }

  // ---- c0 tile w: ctx @ Wc^T + bc (3-term), fp32 resident ----
  f32x4 cst;
  {
    f32x4 acc = *(const f32x4*)(bc + 16 * w + 4 * g);
#pragma unroll
    for (int kk = 0; kk < 4; kk++) {
      bf16x8 aH = ldfrag_g(wccH + (16 * w + c) * 128 + 32 * kk + 8 * g);
      bf16x8 aL = ldfrag_g(wccL + (16 * w + c) * 128 + 32 * kk + 8 * g);
      acc = MFMA16(aH, xcH[kk], acc);
      acc = MFMA16(aH, xcL[kk], acc);
      acc = MFMA16(aL, xcH[kk], acc);
    }
    cst = acc;
  }

  // ---- static input frags hi/lo: [ball(2), enc(64), 0-pad] K=96 ----
  bf16x8 xsH[3], xsL[3];
#pragma unroll
  for (int kk = 0; kk < 3; kk++) {
    float v[8];
#pragma unroll
    for (int j = 0; j < 8; j++) {
      int k = 32 * kk + 8 * g + j;
      float val = 0.f;
      if (k < 2) val = ball[row * 2 + k];
      else if (k < 66) val = enc[row * 64 + (k - 2)];
      v[j] = val;
    }
    split8(v, xsH[kk], xsL[kk]);
  }

  // ---- gates_static for my 4 tiles (tl=4j+w), fp32 resident ----
  f32x4 gsf[4];
#pragma unroll
  for (int j = 0; j < 4; j++) {
    const int tl = 4 * j + w;
    f32x4 acc = *(const f32x4*)(bsum + 16 * tl + 4 * g);
#pragma unroll
    for (int kk = 0; kk < 3; kk++) {
      bf16x8 aH = ldfrag_g(wstatH + (16 * tl + c) * 96 + 32 * kk + 8 * g);
      bf16x8 aL = ldfrag_g(wstatL + (16 * tl + c) * 96 + 32 * kk + 8 * g);
      acc = MFMA16(aH, xsH[kk], acc);
      acc = MFMA16(aH, xsL[kk], acc);
      acc = MFMA16(aL, xsH[kk], acc);
    }
    gsf[j] = acc;
  }

  // ---- W_out zero-padded 16x64 A-tile (rows 0,1) for pred MFMA ----
  bf16x8 wof[2];
#pragma unroll
  for (int f = 0; f < 2; f++) {
    float v[8];
#pragma unroll
    for (int j = 0; j < 8; j++) {
      int k = 32 * f + 8 * g + j;
      v[j] = (c < 2) ? woutf[c * 64 + k] : 0.f;
    }
    bf16x8 dummy;
    split8(v, wof[f], dummy);
  }
  const float bo0 = bout[0], bo1 = bout[1];

  // ---- W_eff hi/lo frags for my 4 tiles (64 VGPRs) ----
  bf16x8 wfH[4][2], wfL[4][2];
#pragma unroll
  for (int j = 0; j < 4; j++) {
    const int tl = 4 * j + w;
#pragma unroll
    for (int f = 0; f < 2; f++) {
      wfH[j][f] = ldfrag_g(weffH + (16 * tl + c) * 64 + 32 * f + 8 * g);
      wfL[j][f] = ldfrag_g(weffL + (16 * tl + c) * 64 + 32 * f + 8 * g);
    }
  }

  __syncthreads();  // h0 visible to all waves

  // ---- step 0 (peeled): W_hh streamed from global, gs - wpb ----
  {
    bf16x8 hh0 = HFRAG(hH_sh[0], 0), hh1 = HFRAG(hH_sh[0], 1);
    bf16x8 hl0 = HFRAG(hL_sh[0], 0), hl1 = HFRAG(hL_sh[0], 1);
    f32x4 av[4];
#pragma unroll
    for (int j = 0; j < 4; j++) {
      const int tl = 4 * j + w;
      f32x4 acc = gsf[j] - *(const f32x4*)(wpbv + 16 * tl + 4 * g);
      bf16x8 aH0 = ldfrag_g(whhH + (16 * tl + c) * 64 + 8 * g);
      bf16x8 aH1 = ldfrag_g(whhH + (16 * tl + c) * 64 + 32 + 8 * g);
      bf16x8 aL0 = ldfrag_g(whhL + (16 * tl + c) * 64 + 8 * g);
      bf16x8 aL1 = ldfrag_g(whhL + (16 * tl + c) * 64 + 32 + 8 * g);
      acc = MFMA16(aH0, hh0, acc);
      acc = MFMA16(aH1, hh1, acc);
      acc = MFMA16(aH0, hl0, acc);
      acc = MFMA16(aH1, hl1, acc);
      acc = MFMA16(aL0, hh0, acc);
      acc = MFMA16(aL1, hh1, acc);
      av[j] = acc;
    }
    u32 w0h, w1h, w0l, w1l;
    nonlin4(av[0], av[1], av[2], av[3], cst, w0h, w1h, w0l, w1l);
    HWRITE(hH_sh[1], w, w0h, w1h);
    HWRITE(hL_sh[1], w, w0l, w1l);
    __syncthreads();
  }

  // ---- steps 1..63 ----
#pragma unroll 1
  for (int k = 1; k < 64; k++) {
    const int rb = k & 1, wb = rb ^ 1;
    bf16x8 hh0 = HFRAG(hH_sh[rb], 0), hh1 = HFRAG(hH_sh[rb], 1);
    bf16x8 hl0 = HFRAG(hL_sh[rb], 0), hl1 = HFRAG(hL_sh[rb], 1);
    if (((k - 1) & 3) == w) {  // round-robin pred_{k-1} from h_{k-1}
      f32x4 pacc = {bo0, bo1, 0.f, 0.f};
      pacc = MFMA16(wof[0], hh0, pacc);
      pacc = MFMA16(wof[1], hh1, pacc);
      if (g == 0) {
        f32x2 pr = {pacc[0], pacc[1]};
        *(f32x2*)((char*)p_sh + c * 512 + (((k - 1) * 8) ^ ((c & 7) << 3))) = pr;
      }
    }
    f32x4 av[4];
#pragma unroll
    for (int j = 0; j < 4; j++) {
      f32x4 acc = gsf[j];
      acc = MFMA16(wfH[j][0], hh0, acc);
      acc = MFMA16(wfH[j][1], hh1, acc);
      acc = MFMA16(wfH[j][0], hl0, acc);
      acc = MFMA16(wfH[j][1], hl1, acc);
      acc = MFMA16(wfL[j][0], hh0, acc);
      acc = MFMA16(wfL[j][1], hh1, acc);
      av[j] = acc;
    }
    u32 w0h, w1h, w0l, w1l;
    nonlin4(av[0], av[1], av[2], av[3], cst, w0h, w1h, w0l, w1l);
    HWRITE(hH_sh[wb], w, w0h, w1h);
    HWRITE(hL_sh[wb], w, w0l, w1l);
    __syncthreads();
  }

  // ---- final pred_63 from h_63 (in buf0) by wave 3 ----
  if (w == 3) {
    bf16x8 hh0 = HFRAG(hH_sh[0], 0), hh1 = HFRAG(hH_sh[0], 1);
    f32x4 pacc = {bo0, bo1, 0.f, 0.f};
    pacc = MFMA16(wof[0], hh0, pacc);
    pacc = MFMA16(wof[1], hh1, pacc);
    if (g == 0) {
      f32x2 pr = {pacc[0], pacc[1]};
      *(f32x2*)((char*)p_sh + c * 512 + ((63 * 8) ^ ((c & 7) << 3))) = pr;
    }
  }
  __syncthreads();

  // ---- coalesced flush: out[b][t][2], wave w handles rows 4p+w ----
#pragma unroll
  for (int p = 0; p < 4; p++) {
    const int r = 4 * p + w;
    f32x2 v = *(const f32x2*)((const char*)p_sh + r * 512 + ((lane * 8) ^ ((r & 7) << 3)));
    *(f32x2*)(out + (size_t)(b0 + r) * 128 + lane * 2) = v;
  }
}

extern "C" void kernel_launch(void* const* d_in, const int* in_sizes, int n_in,
                              void* d_out, int out_size, void* d_ws, size_t ws_size,
                              hipStream_t stream) {
  const float* ctx = (const float*)d_in[0];
  const float* enc = (const float*)d_in[1];
  const float* ball = (const float*)d_in[2];
  const float* Wh = (const float*)d_in[3];
  const float* bh = (const float*)d_in[4];
  const float* Wc = (const float*)d_in[5];
  const float* bc = (const float*)d_in[6];
  const float* Wih = (const float*)d_in[7];
  const float* Whh = (const float*)d_in[8];
  const float* bih = (const float*)d_in[9];
  const float* bhh = (const float*)d_in[10];
  const float* Wout = (const float*)d_in[11];
  const float* bout = (const float*)d_in[12];
  float* out = (float*)d_out;

  char* ws = (char*)d_ws;
  u16* weffH = (u16*)(ws + 0);        // 256*64*2 = 32768
  u16* weffL = (u16*)(ws + 32768);    // 32768
  u16* whhH = (u16*)(ws + 65536);     // 32768
  u16* whhL = (u16*)(ws + 98304);     // 32768
  u16* wstatH = (u16*)(ws + 131072);  // 256*96*2 = 49152
  u16* wstatL = (u16*)(ws + 180224);  // 49152
  u16* whcH = (u16*)(ws + 229376);    // 64*128*2 = 16384
  u16* whcL = (u16*)(ws + 245760);    // 16384
  u16* wccH = (u16*)(ws + 262144);    // 16384
  u16* wccL = (u16*)(ws + 278528);    // 16384
  float* bsum = (float*)(ws + 294912);
  float* wpbv = (float*)(ws + 295936);

  const int B = in_sizes[0] / 128;

  setup_k<<<1, 256, 0, stream>>>(Wh, Wc, Wih, Whh, bih, bhh, Wout, bout, weffH, weffL,
                                 whhH, whhL, wstatH, wstatL, whcH, whcL, wccH, wccL,
                                 bsum, wpbv);
  traj_main<<<B / 16, 256, 0, stream>>>(ctx, enc, ball, bh, bc, bout, Wout, weffH, weffL,
                                        whhH, whhL, wstatH, wstatL, whcH, whcL, wccH,
                                        wccL, bsum, wpbv, out);
}

// Round 8
// 633.850 us; speedup vs baseline: 1.2818x; 1.0324x over previous
//
#include <hip/hip_runtime.h>
#include <hip/hip_bf16.h>
#include <stdint.h>

// TrajectoryDecoder: B=65536 fused LSTM rollout, H=64, T=64.
// Round 7 kernel (resubmit; round-7 bench was a GPU-acquisition timeout).
// BISECT of the round-4 failure. Base = round-3 kernel (passed, 579us) +
// ONLY the weight pre-scaling half of round 4:
//  - setup_k scales gate rows: i/f/o by -log2e, g by +2log2e (weff/whh/wstat/
//    bsum/wpbv). h-state matrices (whc/wcc) unscaled.
//  - nonlin4 consumes pre-scaled args: sigm=rcp(1+exp2(x')), tanh=1-2*rcp(...),
//    fma forms, no runtime gate-arg muls.
//  - ALL split/pack helpers are round-3's union-based RNE versions (the
//    round-4 bit-twiddle rewrites are EXCLUDED — prime suspect for the fail).

typedef unsigned short u16;
typedef unsigned int u32;
typedef __bf16 bf16x8 __attribute__((ext_vector_type(8)));
typedef u16 u16x8 __attribute__((ext_vector_type(8)));
typedef float f32x4 __attribute__((ext_vector_type(4)));
typedef float f32x2 __attribute__((ext_vector_type(2)));

#define MFMA16(a, b, c) __builtin_amdgcn_mfma_f32_16x16x32_bf16((a), (b), (c), 0, 0, 0)

#define SCL_SIG (-1.442695040888963f)   // -log2(e)
#define SCL_TANH (2.885390081777927f)   // +2*log2(e)

__device__ __forceinline__ u16 f2bf(float f) {
  __bf16 h = (__bf16)f;
  return __builtin_bit_cast(u16, h);
}
__device__ __forceinline__ float bf2f(u16 u) {
  return __builtin_bit_cast(float, ((u32)u) << 16);
}
__device__ __forceinline__ u32 pkbf(float lo, float hi) {
  union { __bf16 b[2]; u32 u; } p;
  p.b[0] = (__bf16)lo;
  p.b[1] = (__bf16)hi;
  return p.u;
}
__device__ __forceinline__ bf16x8 ldfrag_g(const u16* p) {
  u16x8 v = *(const u16x8*)p;
  return __builtin_bit_cast(bf16x8, v);
}
// split fp32[8] -> bf16 hi + bf16 lo fragments (round-3 union/RNE version)
__device__ __forceinline__ void split8(const float* v, bf16x8& hi, bf16x8& lo) {
  union { u16 s[8]; bf16x8 b; } H, L;
#pragma unroll
  for (int i = 0; i < 8; i++) {
    u16 h = f2bf(v[i]);
    H.s[i] = h;
    L.s[i] = f2bf(v[i] - bf2f(h));
  }
  hi = H.b;
  lo = L.b;
}

// gates pre-scaled: ai/af/ao = -log2e*x, ag = +2log2e*x
__device__ __forceinline__ void nonlin4(const f32x4 ai, const f32x4 af, const f32x4 ag,
                                        const f32x4 ao, f32x4& crow, u32& w0h, u32& w1h,
                                        u32& w0l, u32& w1l) {
  float hi[4], lo[4];
#pragma unroll
  for (int q = 0; q < 4; q++) {
    float iv = __builtin_amdgcn_rcpf(1.f + __builtin_amdgcn_exp2f(ai[q]));
    float fv = __builtin_amdgcn_rcpf(1.f + __builtin_amdgcn_exp2f(af[q]));
    float ov = __builtin_amdgcn_rcpf(1.f + __builtin_amdgcn_exp2f(ao[q]));
    float rg = __builtin_amdgcn_rcpf(1.f + __builtin_amdgcn_exp2f(ag[q]));
    float gv = __builtin_fmaf(rg, -2.f, 1.f);
    float cc = __builtin_fmaf(fv, crow[q], iv * gv);
    crow[q] = cc;
    float r2 = __builtin_amdgcn_rcpf(1.f + __builtin_amdgcn_exp2f(cc * SCL_TANH));
    float hh = __builtin_fmaf(r2, ov * -2.f, ov);
    u16 h16 = f2bf(hh);
    hi[q] = bf2f(h16);
    lo[q] = hh - hi[q];
  }
  w0h = pkbf(hi[0], hi[1]);
  w1h = pkbf(hi[2], hi[3]);
  w0l = pkbf(lo[0], lo[1]);
  w1l = pkbf(lo[2], lo[3]);
}

// ---------------- setup kernel: pre-scaled hi/lo bf16 weights ----------------
__global__ void setup_k(const float* __restrict__ Wh_ctx, const float* __restrict__ Wc_ctx,
                        const float* __restrict__ W_ih, const float* __restrict__ W_hh,
                        const float* __restrict__ b_ih, const float* __restrict__ b_hh,
                        const float* __restrict__ W_out, const float* __restrict__ b_out,
                        u16* __restrict__ weffH, u16* __restrict__ weffL,
                        u16* __restrict__ whhH, u16* __restrict__ whhL,
                        u16* __restrict__ wstatH, u16* __restrict__ wstatL,
                        u16* __restrict__ whcH, u16* __restrict__ whcL,
                        u16* __restrict__ wccH, u16* __restrict__ wccL,
                        float* __restrict__ bsum, float* __restrict__ wpbv) {
  int gr = (int)threadIdx.x;       // 0..255, one gate row each
  const int gate = gr >> 6;        // 0=i,1=f,2=g,3=o
  const float s = (gate == 2) ? SCL_TANH : SCL_SIG;
  float wp0 = W_ih[gr * 68 + 0];
  float wp1 = W_ih[gr * 68 + 1];
  for (int k = 0; k < 64; k++) {
    float whh = s * W_hh[gr * 64 + k];
    u16 h = f2bf(whh);
    whhH[gr * 64 + k] = h;
    whhL[gr * 64 + k] = f2bf(whh - bf2f(h));
    float we = s * (W_hh[gr * 64 + k] + wp0 * W_out[k] + wp1 * W_out[64 + k]);
    u16 eh = f2bf(we);
    weffH[gr * 64 + k] = eh;
    weffL[gr * 64 + k] = f2bf(we - bf2f(eh));
  }
  for (int k = 0; k < 96; k++) {
    float v = (k < 66) ? s * W_ih[gr * 68 + 2 + k] : 0.f;
    u16 h = f2bf(v);
    wstatH[gr * 96 + k] = h;
    wstatL[gr * 96 + k] = f2bf(v - bf2f(h));
  }
  float wpb_ = s * (wp0 * b_out[0] + wp1 * b_out[1]);
  wpbv[gr] = wpb_;
  bsum[gr] = s * (b_ih[gr] + b_hh[gr]) + wpb_;
  if (gr < 64) {
    for (int k = 0; k < 128; k++) {
      float a = Wh_ctx[gr * 128 + k];
      u16 ah = f2bf(a);
      whcH[gr * 128 + k] = ah;
      whcL[gr * 128 + k] = f2bf(a - bf2f(ah));
      float b = Wc_ctx[gr * 128 + k];
      u16 bh_ = f2bf(b);
      wccH[gr * 128 + k] = bh_;
      wccL[gr * 128 + k] = f2bf(b - bf2f(bh_));
    }
  }
}

// LDS h buffers: [row c][64 bf16] = 128B rows, XOR-swizzled 16B slots.
#define HFRAG(base, f) \
  ldfrag_g((const u16*)((const char*)(base) + c * 128 + (((16 * g) + 64 * (f)) ^ sw4)))

#define HWRITE(base, grp, w0, w1)                                \
  do {                                                           \
    char* bp_ = (char*)(base) + c * 128;                         \
    *(u32*)(bp_ + ((32 * (grp) + 8 * g) ^ sw4)) = (w0);          \
    *(u32*)(bp_ + ((32 * (grp) + 8 * g + 4) ^ sw4)) = (w1);      \
  } while (0)

// ---------------- main fused kernel: 4 waves/block, h-split ----------------
__global__ __launch_bounds__(256, 3) void traj_main(
    const float* __restrict__ ctx, const float* __restrict__ enc,
    const float* __restrict__ ball, const float* __restrict__ bh,
    const float* __restrict__ bc, const float* __restrict__ bout,
    const float* __restrict__ woutf, const u16* __restrict__ weffH,
    const u16* __restrict__ weffL, const u16* __restrict__ whhH,
    const u16* __restrict__ whhL, const u16* __restrict__ wstatH,
    const u16* __restrict__ wstatL, const u16* __restrict__ whcH,
    const u16* __restrict__ whcL, const u16* __restrict__ wccH,
    const u16* __restrict__ wccL, const float* __restrict__ bsum,
    const float* __restrict__ wpbv, float* __restrict__ out) {
  __shared__ __align__(16) u16 hH_sh[2][16 * 64];    // h hi, double-buffered
  __shared__ __align__(16) u16 hL_sh[2][16 * 64];    // h lo
  __shared__ __align__(16) float p_sh[16 * 64 * 2];  // preds

  const int tid = (int)threadIdx.x;
  const int lane = tid & 63;
  const int w = tid >> 6;    // wave id 0..3: owns h-units [16w,16w+16)
  const int c = lane & 15;   // batch row within tile (MFMA col)
  const int g = lane >> 4;   // lane group
  const int sw4 = (c & 7) << 4;
  const int b0 = (int)blockIdx.x * 16;
  const size_t row = (size_t)(b0 + c);

  // ---- context B-frags hi/lo (K=128 -> 4 frags each) ----
  bf16x8 xcH[4], xcL[4];
#pragma unroll
  for (int kk = 0; kk < 4; kk++) {
    const float* p = ctx + row * 128 + 32 * kk + 8 * g;
    f32x4 a = *(const f32x4*)p;
    f32x4 b = *(const f32x4*)(p + 4);
    float v[8] = {a[0], a[1], a[2], a[3], b[0], b[1], b[2], b[3]};
    split8(v, xcH[kk], xcL[kk]);
  }

  // ---- h0 tile w: ctx @ Wh^T + bh (3-term) -> LDS buf0 ----
  {
    f32x4 acc = *(const f32x4*)(bh + 16 * w + 4 * g);
#pragma unroll
    for (int kk = 0; kk < 4; kk++) {
      bf16x8 aH = ldfrag_g(whcH + (16 * w + c) * 128 + 32 * kk + 8 * g);
      bf16x8 aL = ldfrag_g(whcL + (16 * w + c) * 128 + 32 * kk + 8 * g);
      acc = MFMA16(aH, xcH[kk], acc);
      acc = MFMA16(aH, xcL[kk], acc);
      acc = MFMA16(aL, xcH[kk], acc);
    }
    float hi_[4], lo_[4];
#pragma unroll
    for (int q = 0; q < 4; q++) {
      u16 h16 = f2bf(acc[q]);
      hi_[q] = bf2f(h16);
      lo_[q] = acc[q] - hi_[q];
    }
    HWRITE(hH_sh[0], w, pkbf(hi_[0], hi_[1]), pkbf(hi_[2], hi_[3]));
    HWRITE(hL_sh[0], w, pkbf(lo_[0], lo_[1]), pkbf(lo_[2], lo_[3]));
  }

  // ---- c0 tile w: ctx @ Wc^T + bc (3-term), fp32 resident ----
  f32x4 cst;
  {
    f32x4 acc = *(const f32x4*)(bc + 16 * w + 4 * g);
#pragma unroll
    for (int kk = 0; kk < 4; kk++) {
      bf16x8 aH = ldfrag_g(wccH + (16 * w + c) * 128 + 32 * kk + 8 * g);
      bf16x8 aL = ldfrag_g(wccL + (16 * w + c) * 128 + 32 * kk + 8 * g);
      acc = MFMA16(aH, xcH[kk], acc);
      acc = MFMA16(aH, xcL[kk], acc);
      acc = MFMA16(aL, xcH[kk], acc);
    }
    cst = acc;
  }

  // ---- static input frags hi/lo: [ball(2), enc(64), 0-pad] K=96 ----
  bf16x8 xsH[3], xsL[3];
#pragma unroll
  for (int kk = 0; kk < 3; kk++) {
    float v[8];
#pragma unroll
    for (int j = 0; j < 8; j++) {
      int k = 32 * kk + 8 * g + j;
      float val = 0.f;
      if (k < 2) val = ball[row * 2 + k];
      else if (k < 66) val = enc[row * 64 + (k - 2)];
      v[j] = val;
    }
    split8(v, xsH[kk], xsL[kk]);
  }

  // ---- gates_static for my 4 tiles (tl=4j+w), fp32 resident (pre-scaled) ----
  f32x4 gsf[4];
#pragma unroll
  for (int j = 0; j < 4; j++) {
    const int tl = 4 * j + w;
    f32x4 acc = *(const f32x4*)(bsum + 16 * tl + 4 * g);
#pragma unroll
    for (int kk = 0; kk < 3; kk++) {
      bf16x8 aH = ldfrag_g(wstatH + (16 * tl + c) * 96 + 32 * kk + 8 * g);
      bf16x8 aL = ldfrag_g(wstatL + (16 * tl + c) * 96 + 32 * kk + 8 * g);
      acc = MFMA16(aH, xsH[kk], acc);
      acc = MFMA16(aH, xsL[kk], acc);
      acc = MFMA16(aL, xsH[kk], acc);
    }
    gsf[j] = acc;
  }

  // ---- W_out zero-padded 16x64 A-tile (rows 0,1) for pred MFMA ----
  bf16x8 wof[2];
#pragma unroll
  for (int f = 0; f < 2; f++) {
    float v[8];
#pragma unroll
    for (int j = 0; j < 8; j++) {
      int k = 32 * f + 8 * g + j;
      v[j] = (c < 2) ? woutf[c * 64 + k] : 0.f;
    }
    bf16x8 dummy;
    split8(v, wof[f], dummy);
  }
  const float bo0 = bout[0], bo1 = bout[1];

  // ---- W_eff hi/lo frags for my 4 tiles (64 VGPRs) ----
  bf16x8 wfH[4][2], wfL[4][2];
#pragma unroll
  for (int j = 0; j < 4; j++) {
    const int tl = 4 * j + w;
#pragma unroll
    for (int f = 0; f < 2; f++) {
      wfH[j][f] = ldfrag_g(weffH + (16 * tl + c) * 64 + 32 * f + 8 * g);
      wfL[j][f] = ldfrag_g(weffL + (16 * tl + c) * 64 + 32 * f + 8 * g);
    }
  }

  __syncthreads();  // h0 visible to all waves

  // ---- step 0 (peeled): W_hh streamed from global, gs - wpb ----
  {
    bf16x8 hh0 = HFRAG(hH_sh[0], 0), hh1 = HFRAG(hH_sh[0], 1);
    bf16x8 hl0 = HFRAG(hL_sh[0], 0), hl1 = HFRAG(hL_sh[0], 1);
    f32x4 av[4];
#pragma unroll
    for (int j = 0; j < 4; j++) {
      const int tl = 4 * j + w;
      f32x4 acc = gsf[j] - *(const f32x4*)(wpbv + 16 * tl + 4 * g);
      bf16x8 aH0 = ldfrag_g(whhH + (16 * tl + c) * 64 + 8 * g);
      bf16x8 aH1 = ldfrag_g(whhH + (16 * tl + c) * 64 + 32 + 8 * g);
      bf16x8 aL0 = ldfrag_g(whhL + (16 * tl + c) * 64 + 8 * g);
      bf16x8 aL1 = ldfrag_g(whhL + (16 * tl + c) * 64 + 32 + 8 * g);
      acc = MFMA16(aH0, hh0, acc);
      acc = MFMA16(aH1, hh1, acc);
      acc = MFMA16(aH0, hl0, acc);
      acc = MFMA16(aH1, hl1, acc);
      acc = MFMA16(aL0, hh0, acc);
      acc = MFMA16(aL1, hh1, acc);
      av[j] = acc;
    }
    u32 w0h, w1h, w0l, w1l;
    nonlin4(av[0], av[1], av[2], av[3], cst, w0h, w1h, w0l, w1l);
    HWRITE(hH_sh[1], w, w0h, w1h);
    HWRITE(hL_sh[1], w, w0l, w1l);
    __syncthreads();
  }

  // ---- steps 1..63 ----
#pragma unroll 1
  for (int k = 1; k < 64; k++) {
    const int rb = k & 1, wb = rb ^ 1;
    bf16x8 hh0 = HFRAG(hH_sh[rb], 0), hh1 = HFRAG(hH_sh[rb], 1);
    bf16x8 hl0 = HFRAG(hL_sh[rb], 0), hl1 = HFRAG(hL_sh[rb], 1);
    if (((k - 1) & 3) == w) {  // round-robin pred_{k-1} from h_{k-1}
      f32x4 pacc = {bo0, bo1, 0.f, 0.f};
      pacc = MFMA16(wof[0], hh0, pacc);
      pacc = MFMA16(wof[1], hh1, pacc);
      if (g == 0) {
        f32x2 pr = {pacc[0], pacc[1]};
        *(f32x2*)((char*)p_sh + c * 512 + (((k - 1) * 8) ^ ((c & 7) << 3))) = pr;
      }
    }
    f32x4 av[4];
#pragma unroll
    for (int j = 0; j < 4; j++) {
      f32x4 acc = gsf[j];
      acc = MFMA16(wfH[j][0], hh0, acc);
      acc = MFMA16(wfH[j][1], hh1, acc);
      acc = MFMA16(wfH[j][0], hl0, acc);
      acc = MFMA16(wfH[j][1], hl1, acc);
      acc = MFMA16(wfL[j][0], hh0, acc);
      acc = MFMA16(wfL[j][1], hh1, acc);
      av[j] = acc;
    }
    u32 w0h, w1h, w0l, w1l;
    nonlin4(av[0], av[1], av[2], av[3], cst, w0h, w1h, w0l, w1l);
    HWRITE(hH_sh[wb], w, w0h, w1h);
    HWRITE(hL_sh[wb], w, w0l, w1l);
    __syncthreads();
  }

  // ---- final pred_63 from h_63 (in buf0) by wave 3 ----
  if (w == 3) {
    bf16x8 hh0 = HFRAG(hH_sh[0], 0), hh1 = HFRAG(hH_sh[0], 1);
    f32x4 pacc = {bo0, bo1, 0.f, 0.f};
    pacc = MFMA16(wof[0], hh0, pacc);
    pacc = MFMA16(wof[1], hh1, pacc);
    if (g == 0) {
      f32x2 pr = {pacc[0], pacc[1]};
      *(f32x2*)((char*)p_sh + c * 512 + ((63 * 8) ^ ((c & 7) << 3))) = pr;
    }
  }
  __syncthreads();

  // ---- coalesced flush: out[b][t][2], wave w handles rows 4p+w ----
#pragma unroll
  for (int p = 0; p < 4; p++) {
    const int r = 4 * p + w;
    f32x2 v = *(const f32x2*)((const char*)p_sh + r * 512 + ((lane * 8) ^ ((r & 7) << 3)));
    *(f32x2*)(out + (size_t)(b0 + r) * 128 + lane * 2) = v;
  }
}

extern "C" void kernel_launch(void* const* d_in, const int* in_sizes, int n_in,
                              void* d_out, int out_size, void* d_ws, size_t ws_size,
                              hipStream_t stream) {
  const float* ctx = (const float*)d_in[0];
  const float* enc = (const float*)d_in[1];
  const float* ball = (const float*)d_in[2];
  const float* Wh = (const float*)d_in[3];
  const float* bh = (const float*)d_in[4];
  const float* Wc = (const float*)d_in[5];
  const float* bc = (const float*)d_in[6];
  const float* Wih = (const float*)d_in[7];
  const float* Whh = (const float*)d_in[8];
  const float* bih = (const float*)d_in[9];
  const float* bhh = (const float*)d_in[10];
  const float* Wout = (const float*)d_in[11];
  const float* bout = (const float*)d_in[12];
  float* out = (float*)d_out;

  char* ws = (char*)d_ws;
  u16* weffH = (u16*)(ws + 0);        // 256*64*2 = 32768
  u16* weffL = (u16*)(ws + 32768);    // 32768
  u16* whhH = (u16*)(ws + 65536);     // 32768
  u16* whhL = (u16*)(ws + 98304);     // 32768
  u16* wstatH = (u16*)(ws + 131072);  // 256*96*2 = 49152
  u16* wstatL = (u16*)(ws + 180224);  // 49152
  u16* whcH = (u16*)(ws + 229376);    // 64*128*2 = 16384
  u16* whcL = (u16*)(ws + 245760);    // 16384
  u16* wccH = (u16*)(ws + 262144);    // 16384
  u16* wccL = (u16*)(ws + 278528);    // 16384
  float* bsum = (float*)(ws + 294912);
  float* wpbv = (float*)(ws + 295936);

  const int B = in_sizes[0] / 128;

  setup_k<<<1, 256, 0, stream>>>(Wh, Wc, Wih, Whh, bih, bhh, Wout, bout, weffH, weffL,
                                 whhH, whhL, wstatH, wstatL, whcH, whcL, wccH, wccL,
                                 bsum, wpbv);
  traj_main<<<B / 16, 256, 0, stream>>>(ctx, enc, ball, bh, bc, bout, Wout, weffH, weffL,
                                        whhH, whhL, wstatH, wstatL, whcH, whcL, wccH,
                                        wccL, bsum, wpbv, out);
}